// Round 1
// baseline (218.129 us; speedup 1.0000x reference)
//
#include <hip/hip_runtime.h>
#include <math.h>

// CapsNet dynamic routing, fused per-(batch, out_capsule) block.
// u:      [256][1152][8]  f32
// weight: [1152][10][8][16] f32
// out v:  [256][10][16] f32
//
// Routing decomposes independently per (b, j): softmax over in_caps is per
// (b,j); s, squash, a, b-update all stay within the (b,j) slice. One block
// computes u_hat[b,:,j,:] (1152x16) into LDS once, then runs all 3 routing
// iterations from LDS. No workspace needed.

#define IC 1152
#define OC 10
#define ID 8
#define OD 16
#define NBATCH 256
#define STRIDE 20  // LDS row stride (floats) for uhat: 16 data + 4 pad, keeps
                   // float4 rows 16B-aligned and spreads banks (20*i mod 32 cycles 8 values)

__global__ __launch_bounds__(1024, 1)
void caps_route_kernel(const float* __restrict__ u,
                       const float* __restrict__ W,
                       float* __restrict__ out) {
    extern __shared__ float smem[];
    float* uhat = smem;                   // IC*STRIDE = 23040 floats
    float* blog = uhat + IC * STRIDE;     // IC
    float* cexp = blog + IC;              // IC
    float* red  = cexp + IC;              // 16 waves * 16 m = 256
    float* vsh  = red + 256;              // 16
    float* scal = vsh + 16;               // [0]=max, [1]=1/sumexp
    float* wred = scal + 2;               // 16 (per-wave reduction scratch)

    const int t  = threadIdx.x;
    const int bx = blockIdx.x;

    // XCD-aware (b,j) mapping: assume xcd = bx & 7 (perf heuristic only).
    // XCD x<8 owns j=x; j=8 spread over XCDs 0..3, j=9 over XCDs 4..7.
    // -> each XCD touches at most 2 weight slices (1.18 MB < 4 MB L2).
    int x = bx & 7, s = bx >> 3;
    int b, j;
    if (s < 256) { j = x; b = s; }
    else { int s2 = s - 256; j = 8 + (x >> 2); b = ((x & 3) << 6) + s2; }

    // ---- Phase A: uhat[i][m] = sum_n u[b,i,n] * W[i,j,n,m] -> LDS ----
    {
        const int mq = t & 3;             // which float4 of the 16-m row
        for (int i = (t >> 2); i < IC; i += 256) {
            const float4* wrow = (const float4*)(W + (size_t)(i * OC + j) * 128);
            const float*  up   = u + (size_t)b * (IC * ID) + i * ID;
            float4 ua = *(const float4*)up;
            float4 ub = *(const float4*)(up + 4);
            float uu[8] = {ua.x, ua.y, ua.z, ua.w, ub.x, ub.y, ub.z, ub.w};
            float4 acc = {0.f, 0.f, 0.f, 0.f};
#pragma unroll
            for (int n = 0; n < 8; ++n) {
                float4 w4 = wrow[n * 4 + mq];
                acc.x += uu[n] * w4.x;
                acc.y += uu[n] * w4.y;
                acc.z += uu[n] * w4.z;
                acc.w += uu[n] * w4.w;
            }
            *(float4*)&uhat[i * STRIDE + mq * 4] = acc;
        }
    }
    for (int i = t; i < IC; i += 1024) blog[i] = 0.f;
    __syncthreads();

    const int lane = t & 63;
    const int wid  = t >> 6;

    for (int r = 0; r < 3; ++r) {
        // ---- softmax over i: max ----
        float lmax = -3.4e38f;
        for (int i = t; i < IC; i += 1024) lmax = fmaxf(lmax, blog[i]);
#pragma unroll
        for (int o = 32; o >= 1; o >>= 1) lmax = fmaxf(lmax, __shfl_xor(lmax, o, 64));
        if (lane == 0) wred[wid] = lmax;
        __syncthreads();
        if (t == 0) {
            float m0 = wred[0];
            for (int w = 1; w < 16; ++w) m0 = fmaxf(m0, wred[w]);
            scal[0] = m0;
        }
        __syncthreads();
        const float bmax = scal[0];

        // ---- exp + sum ----
        float lsum = 0.f;
        for (int i = t; i < IC; i += 1024) {
            float e = __expf(blog[i] - bmax);
            cexp[i] = e;
            lsum += e;
        }
#pragma unroll
        for (int o = 32; o >= 1; o >>= 1) lsum += __shfl_xor(lsum, o, 64);
        if (lane == 0) wred[wid] = lsum;
        __syncthreads();
        if (t == 0) {
            float s0 = 0.f;
            for (int w = 0; w < 16; ++w) s0 += wred[w];
            scal[1] = 1.0f / s0;
        }
        __syncthreads();

        // ---- s[m] = inv_sum * sum_i cexp[i] * uhat[i][m] ----
        {
            const int g = t >> 4, m = t & 15;
            float acc = 0.f;
            for (int i = g; i < IC; i += 64)
                acc += cexp[i] * uhat[i * STRIDE + m];
            // in-wave reduce over the 4 g-groups sharing this wave
            acc += __shfl_xor(acc, 16, 64);
            acc += __shfl_xor(acc, 32, 64);
            if (lane < 16) red[wid * 16 + lane] = acc;
        }
        __syncthreads();

        // ---- cross-wave reduce + squash (first 16 threads) ----
        if (t < 16) {
            float sm = 0.f;
#pragma unroll
            for (int w = 0; w < 16; ++w) sm += red[w * 16 + t];
            sm *= scal[1];
            float p = sm * sm;
            p += __shfl_xor(p, 1, 64);
            p += __shfl_xor(p, 2, 64);
            p += __shfl_xor(p, 4, 64);
            p += __shfl_xor(p, 8, 64);
            // squash: s2/(1+s2) * s / sqrt(s2+eps)
            float sc = p / ((1.0f + p) * sqrtf(p + 1e-8f));
            float vm = sm * sc;
            vsh[t] = vm;
            if (r == 2) out[(size_t)(b * OC + j) * OD + t] = vm;
        }
        __syncthreads();

        if (r < 2) {
            // ---- b[i] += v . uhat[i][:] ----
            float4 v0 = *(float4*)&vsh[0];
            float4 v1 = *(float4*)&vsh[4];
            float4 v2 = *(float4*)&vsh[8];
            float4 v3 = *(float4*)&vsh[12];
            for (int i = t; i < IC; i += 1024) {
                const float4 q0 = *(float4*)&uhat[i * STRIDE + 0];
                const float4 q1 = *(float4*)&uhat[i * STRIDE + 4];
                const float4 q2 = *(float4*)&uhat[i * STRIDE + 8];
                const float4 q3 = *(float4*)&uhat[i * STRIDE + 12];
                float dot = q0.x * v0.x + q0.y * v0.y + q0.z * v0.z + q0.w * v0.w
                          + q1.x * v1.x + q1.y * v1.y + q1.z * v1.z + q1.w * v1.w
                          + q2.x * v2.x + q2.y * v2.y + q2.z * v2.z + q2.w * v2.w
                          + q3.x * v3.x + q3.y * v3.y + q3.z * v3.z + q3.w * v3.w;
                blog[i] += dot;
            }
            __syncthreads();
        }
    }
}

extern "C" void kernel_launch(void* const* d_in, const int* in_sizes, int n_in,
                              void* d_out, int out_size, void* d_ws, size_t ws_size,
                              hipStream_t stream) {
    const float* u = (const float*)d_in[0];
    const float* W = (const float*)d_in[1];
    float* out = (float*)d_out;

    const size_t shmem = (size_t)(IC * STRIDE + IC + IC + 256 + 16 + 2 + 16) * sizeof(float);
    // >64KB dynamic LDS needs the attribute; idempotent, capture-safe (not a stream op).
    hipFuncSetAttribute((const void*)caps_route_kernel,
                        hipFuncAttributeMaxDynamicSharedMemorySize, (int)shmem);

    caps_route_kernel<<<NBATCH * OC, 1024, shmem, stream>>>(u, W, out);
}